// Round 8
// baseline (93.331 us; speedup 1.0000x reference)
//
#include <hip/hip_runtime.h>
#include <hip/hip_cooperative_groups.h>

namespace cg = cooperative_groups;

#define NN    16384
#define CBN   64
#define SUBV  16
#define KCODE 16
#define DOUTN 1024
#define DEP   4

typedef short bf16x8 __attribute__((ext_vector_type(8)));
typedef float f32x16 __attribute__((ext_vector_type(16)));

static __device__ __forceinline__ unsigned short f2bf(float f) {
  unsigned int u = __float_as_uint(f);
  u += 0x7FFFu + ((u >> 16) & 1u);   // RNE; inputs are normal randn, no NaN/Inf
  return (unsigned short)(u >> 16);
}

// ---------------- fused cooperative kernel ----------------
// 256 blocks x 1024 thr = 1 block/CU, all co-resident (coop launch).
// Block b: colgroup cg16 = b&15 (cols cg16*64..+64), phase-2 rowgroup
// rg16 = b>>4 (rows rg16*1024..+1024).
// Phase 1 (per block): stage split tables (9 KiB LDS); convert its own
//   colgroup's full table Tg -> LDS Tb (128 KiB, bf16, XOR-swizzled) —
//   NO global Tswz roundtrip, NO gld16 staging; encode rows b*64..+64 via
//   direct global tree-walk (a subvec = exactly one 64B line; 4 scalar
//   loads/row replace all xs staging) -> codes[n][c] u8.
// grid.sync()
// Phase 2: R7's compute loop, setprio removed (hurts lockstep waves, m190),
//   per-wave chunk stagger ch=(wid+i)&7 to de-burst LDS/code traffic.
__global__ __launch_bounds__(1024, 4) void fused_k(
    const float* __restrict__ x, const int* __restrict__ split_idxs,
    const float* __restrict__ split_vals, const float* __restrict__ Tg,
    const float* __restrict__ bias, unsigned char* __restrict__ codes,
    float* __restrict__ out) {
  __shared__ __align__(16) unsigned int Tb[32768];   // 128 KiB: [ch8][cl8][512 u32]
  __shared__ int   sidxT[DEP * CBN];                 // [d][c]
  __shared__ float svalT[DEP * (KCODE / 2) * CBN];   // [d][e][c]

  const int t = threadIdx.x;
  const int b = blockIdx.x;
  const int cg16 = b & 15, rg16 = b >> 4;

  // ---- phase 1a: split tables -> LDS (transposed, bank = c) ----
  if (t < DEP * CBN) {
    int d = t >> 6, c = t & 63;
    sidxT[t] = split_idxs[c * DEP + d];
  }
  for (int i = t; i < DEP * (KCODE / 2) * CBN; i += 1024) {
    int c = i & 63, de = i >> 6, d = de >> 3, e = de & 7;
    svalT[i] = split_vals[(c * DEP + d) * (KCODE / 2) + e];
  }

  // ---- phase 1b: convert own colgroup table into LDS (swizzled) ----
  // cb = codebook 0..63 -> (ch=cb>>3, cl=cb&7); per (cb): 16 k-rows of
  // 64 cols; u32 write idx within the 512-u32 cl-block:
  // (col*8+kp) ^ (((col>>2)&7)<<2)  — same involution the reads use.
  {
    const int col = t & 63;
    #pragma unroll
    for (int cb0 = 0; cb0 < 4; ++cb0) {
      const int cb = cb0 * 16 + (t >> 6);
      const float* src = Tg + (size_t)cb * KCODE * DOUTN + cg16 * 64 + col;
      float v[16];
      #pragma unroll
      for (int k = 0; k < 16; ++k) v[k] = src[k * DOUTN];   // 256B/wave, L2/L3-warm
      unsigned int* dst = Tb + (cb >> 3) * 4096 + (cb & 7) * 512;
      const unsigned key = (((unsigned)col >> 2) & 7u) << 2;
      #pragma unroll
      for (int kp = 0; kp < 8; ++kp) {
        unsigned int pk = f2bf(v[2 * kp]) | ((unsigned int)f2bf(v[2 * kp + 1]) << 16);
        dst[((unsigned)(col * 8 + kp)) ^ key] = pk;
      }
    }
  }
  __syncthreads();                                   // split tables ready

  // ---- phase 1c: encode rows b*64 .. b*64+64 (direct line reads) ----
  {
    const int c = t & 63, rg = t >> 6;               // 16 groups x 4 rows
    const float* xr = x + (size_t)(b * 64 + rg * 4) * DOUTN + c * SUBV;
    #pragma unroll
    for (int i = 0; i < 4; ++i) {
      int e = 0;
      #pragma unroll
      for (int d = 0; d < DEP; ++d) {
        float xv = xr[i * DOUTN + sidxT[d * 64 + c]];
        float th = svalT[(d * 8 + e) * 64 + c];
        e = 2 * e + (xv > th ? 1 : 0);
      }
      codes[(size_t)(b * 64 + rg * 4 + i) * CBN + c] = (unsigned char)e;
    }
  }

  cg::this_grid().sync();                            // codes + all Tb ready

  // ---- phase 2: one-hot MFMA gather-accumulate ----
  const int wid = t >> 6, lane = t & 63, lrow = lane & 31, h = lane >> 5;
  const int n0 = rg16 * 1024;

  f32x16 acc[2][2];
  #pragma unroll
  for (int rt = 0; rt < 2; ++rt)
    #pragma unroll
    for (int ct = 0; ct < 2; ++ct)
      #pragma unroll
      for (int e = 0; e < 16; ++e) acc[rt][ct][e] = 0.f;

  const unsigned char* crow = codes + (size_t)(n0 + wid * 64 + lrow) * CBN;
  unsigned long long qwA[2], qwB[2];
  {
    const int ch0 = wid & 7;
    qwA[0] = *(const unsigned long long*)(crow + ch0 * 8);
    qwA[1] = *(const unsigned long long*)(crow + 32 * CBN + ch0 * 8);
  }

  #pragma unroll
  for (int i = 0; i < 8; ++i) {
    const int ch = (wid + i) & 7;                    // per-wave stagger
    if (i < 7) {                                     // prefetch next codes
      const int chn = (wid + i + 1) & 7;
      qwB[0] = *(const unsigned long long*)(crow + chn * 8);
      qwB[1] = *(const unsigned long long*)(crow + 32 * CBN + chn * 8);
    }
    const unsigned short* tb = (const unsigned short*)Tb + ch * 8192;
    #pragma unroll
    for (int cl = 0; cl < 8; ++cl) {
      bf16x8 bv[2];
      #pragma unroll
      for (int ct = 0; ct < 2; ++ct) {
        unsigned col_loc = (unsigned)(ct * 32 + lrow);
        unsigned uidx = (unsigned)(cl * 1024)
                      + ((col_loc * 16 + (unsigned)h * 8)
                         ^ (((col_loc >> 2) & 7u) << 3));
        bv[ct] = *(const bf16x8*)(tb + uidx);
      }
      #pragma unroll
      for (int rt = 0; rt < 2; ++rt) {
        int c = (int)((qwA[rt] >> (8 * cl)) & 255);
        int p = c >> 1;
        unsigned s = 0x3F80u << ((c & 1) << 4);      // bf16(1.0) in right half
        union { unsigned int u[4]; bf16x8 v; } A;
        #pragma unroll
        for (int j = 0; j < 4; ++j) A.u[j] = (p == h * 4 + j) ? s : 0u;
        acc[rt][0] = __builtin_amdgcn_mfma_f32_32x32x16_bf16(A.v, bv[0], acc[rt][0], 0, 0, 0);
        acc[rt][1] = __builtin_amdgcn_mfma_f32_32x32x16_bf16(A.v, bv[1], acc[rt][1], 0, 0, 0);
      }
    }
    qwA[0] = qwB[0]; qwA[1] = qwB[1];
  }

  // epilogue: D layout col=lane&31, row=(reg&3)+8*(reg>>2)+4*(lane>>5)
  #pragma unroll
  for (int ct = 0; ct < 2; ++ct) {
    const int col = cg16 * 64 + ct * 32 + lrow;
    const float bval = bias[col];
    #pragma unroll
    for (int rt = 0; rt < 2; ++rt)
      #pragma unroll
      for (int r = 0; r < 16; ++r) {
        int row = n0 + wid * 64 + rt * 32 + (r & 3) + 8 * (r >> 2) + 4 * h;
        out[(size_t)row * DOUTN + col] = acc[rt][ct][r] + bval;
      }
  }
}

extern "C" void kernel_launch(void* const* d_in, const int* in_sizes, int n_in,
                              void* d_out, int out_size, void* d_ws, size_t ws_size,
                              hipStream_t stream) {
  const float* x    = (const float*)d_in[0];
  const int*   sidx = (const int*)d_in[1];
  const float* sval = (const float*)d_in[2];
  const float* Tg   = (const float*)d_in[3];
  const float* bias = (const float*)d_in[4];
  float* out = (float*)d_out;
  unsigned char* codes = (unsigned char*)d_ws;   // 1 MiB: codes[n][c]

  void* args[] = {(void*)&x, (void*)&sidx, (void*)&sval, (void*)&Tg,
                  (void*)&bias, (void*)&codes, (void*)&out};
  hipLaunchCooperativeKernel((const void*)fused_k, dim3(256), dim3(1024),
                             args, 0, stream);
}

// Round 9
// 66.270 us; speedup vs baseline: 1.4083x; 1.4083x over previous
//
#include <hip/hip_runtime.h>

#define NN    16384
#define CBN   64
#define SUBV  16
#define KCODE 16
#define DOUTN 1024
#define DEP   4

typedef short bf16x8 __attribute__((ext_vector_type(8)));
typedef float f32x16 __attribute__((ext_vector_type(16)));

static __device__ __forceinline__ unsigned short f2bf(float f) {
  unsigned int u = __float_as_uint(f);
  u += 0x7FFFu + ((u >> 16) & 1u);   // RNE; inputs are normal randn, no NaN/Inf
  return (unsigned short)(u >> 16);
}

// ---------------- kernel 1: encode only ----------------
// 2048 blocks x 256 thr, 8 rows each -> codes[n][c] (u8, n-major).
// x staged to LDS with quad-granular XOR swizzle (keeps ds_write_b128,
// spreads banks for the random-element tree reads). Proven R7 path.
__global__ __launch_bounds__(256) void encode_k(
    const float* __restrict__ x, const int* __restrict__ split_idxs,
    const float* __restrict__ split_vals, unsigned char* __restrict__ codes) {
  __shared__ __align__(16) float xs[8][SUBV * CBN];
  __shared__ int   sidxT[DEP * CBN];               // [d][c]
  __shared__ float svalT[DEP * (KCODE / 2) * CBN]; // [d][e][c]
  const int t = threadIdx.x;
  if (t < DEP * CBN) {
    int d = t >> 6, c = t & 63;
    sidxT[t] = split_idxs[c * DEP + d];
  }
  for (int i = t; i < DEP * (KCODE / 2) * CBN; i += 256) {
    int c = i & 63, de = i >> 6, d = de >> 3, e = de & 7;
    svalT[i] = split_vals[(c * DEP + d) * (KCODE / 2) + e];
  }
  const int n0 = blockIdx.x * 8;
  const float4* xg = (const float4*)(x + (size_t)n0 * DOUTN);
  #pragma unroll
  for (int i = 0; i < 8; ++i) {                    // 8 rows * 256 float4/row
    int li = t + i * 256;
    int r = li >> 8, cpos = li & 255;
    float4 v = xg[r * 256 + cpos];
    int c = cpos >> 2, q = cpos & 3;
    *(float4*)&xs[r][c * SUBV + ((q ^ (c & 3)) << 2)] = v;
  }
  __syncthreads();
  const int c = t & 63, rg = t >> 6;
  #pragma unroll
  for (int i = 0; i < 2; ++i) {
    int nl = rg * 2 + i;
    int e = 0;
    #pragma unroll
    for (int d = 0; d < DEP; ++d) {
      int si = sidxT[d * 64 + c];
      float xv = xs[nl][c * SUBV + (((si >> 2) ^ (c & 3)) << 2) + (si & 3)];
      float th = svalT[(d * 8 + e) * 64 + c];
      e = 2 * e + (xv > th ? 1 : 0);
    }
    codes[(size_t)(n0 + nl) * CBN + c] = (unsigned char)e;
  }
}

// ---------------- kernel 2: one-hot MFMA gather-accumulate ----------------
// grid (16 colgroups, 16 rowgroups) = 256 blocks = 1/CU; 1024 thr = 16 waves.
// Phase A: convert own colgroup's table Tg (L3-resident, 4 MB unique) directly
//   into LDS Tb (128 KiB bf16, XOR-swizzled) — R8-verified mapping; no global
//   Tswz roundtrip. One barrier.
// Phase B: ct-SPLIT two-pass loop: pass ct computes its 32 cols over all
//   (ch,cl) then writes immediately -> ct=0's HBM writes overlap ct=1's
//   compute (halves the exposed write tail). B-fragments are software-
//   pipelined one iteration ahead (bvP) so ds_read latency hides under
//   MFMA+VALU. Per-wave ch-stagger de-bursts LDS banks.
__global__ __launch_bounds__(1024, 4) void maddness_mfma(
    const float* __restrict__ Tg, const float* __restrict__ bias,
    const unsigned char* __restrict__ codes, float* __restrict__ out) {
  __shared__ __align__(16) unsigned int Tb[32768];   // 128 KiB: [ch8][cl8][512 u32]

  const int t = threadIdx.x;
  const int cg16 = blockIdx.x;
  const int n0 = blockIdx.y * 1024;

  // ---- phase A: convert colgroup table -> LDS (swizzled; R8-verified) ----
  {
    const int col = t & 63;
    #pragma unroll
    for (int cb0 = 0; cb0 < 4; ++cb0) {
      const int cb = cb0 * 16 + (t >> 6);            // codebook 0..63
      const float* src = Tg + (size_t)cb * KCODE * DOUTN + cg16 * 64 + col;
      float v[16];
      #pragma unroll
      for (int k = 0; k < 16; ++k) v[k] = src[k * DOUTN];  // 256B/wave, L3-warm
      unsigned int* dst = Tb + (cb >> 3) * 4096 + (cb & 7) * 512;
      const unsigned key = (((unsigned)col >> 2) & 7u) << 2;
      #pragma unroll
      for (int kp = 0; kp < 8; ++kp) {
        unsigned int pk = f2bf(v[2 * kp]) | ((unsigned int)f2bf(v[2 * kp + 1]) << 16);
        dst[((unsigned)(col * 8 + kp)) ^ key] = pk;
      }
    }
  }
  __syncthreads();                                   // the only barrier

  // ---- phase B: two ct-passes ----
  const int wid = t >> 6, lane = t & 63, lrow = lane & 31, h = lane >> 5;
  const unsigned short* tbase = (const unsigned short*)Tb;
  const unsigned char* crow = codes + (size_t)(n0 + wid * 64 + lrow) * CBN;

  #pragma unroll
  for (int ct = 0; ct < 2; ++ct) {
    f32x16 acc[2];
    #pragma unroll
    for (int rt = 0; rt < 2; ++rt)
      #pragma unroll
      for (int e = 0; e < 16; ++e) acc[rt][e] = 0.f;

    const unsigned col_loc = (unsigned)(ct * 32 + lrow);
    const unsigned rb = (col_loc * 16 + (unsigned)h * 8)   // within-cl u16 idx
                      ^ (((col_loc >> 2) & 7u) << 3);

    const int ch0 = wid & 7;                         // per-wave stagger
    unsigned long long qw0 = *(const unsigned long long*)(crow + ch0 * 8);
    unsigned long long qw1 = *(const unsigned long long*)(crow + 32 * CBN + ch0 * 8);
    bf16x8 bvP = *(const bf16x8*)(tbase + ch0 * 8192 + rb);  // prefetch it=0

    #pragma unroll
    for (int i = 0; i < 8; ++i) {
      const int ch = (wid + i) & 7;
      const unsigned long long q0 = qw0, q1 = qw1;
      if (i < 7) {                                   // prefetch next codes
        const int chn = (wid + i + 1) & 7;
        qw0 = *(const unsigned long long*)(crow + chn * 8);
        qw1 = *(const unsigned long long*)(crow + 32 * CBN + chn * 8);
      }
      #pragma unroll
      for (int cl = 0; cl < 8; ++cl) {
        const bf16x8 bvC = bvP;
        if (!(i == 7 && cl == 7)) {                  // prefetch next B-frag
          const int ni  = (cl == 7) ? i + 1 : i;
          const int ncl = (cl + 1) & 7;
          const int nch = (wid + ni) & 7;
          bvP = *(const bf16x8*)(tbase + nch * 8192 + ncl * 1024 + rb);
        }
        #pragma unroll
        for (int rt = 0; rt < 2; ++rt) {
          const unsigned long long q = rt ? q1 : q0;
          int c = (int)((q >> (8 * cl)) & 255);
          int p = c >> 1;
          unsigned s = 0x3F80u << ((c & 1) << 4);    // bf16(1.0) in right half
          union { unsigned int u[4]; bf16x8 v; } A;
          #pragma unroll
          for (int j = 0; j < 4; ++j) A.u[j] = (p == h * 4 + j) ? s : 0u;
          acc[rt] = __builtin_amdgcn_mfma_f32_32x32x16_bf16(A.v, bvC, acc[rt], 0, 0, 0);
        }
      }
    }

    // write this ct's columns NOW (overlaps next pass's compute)
    const int col = cg16 * 64 + ct * 32 + lrow;
    const float bval = bias[col];
    #pragma unroll
    for (int rt = 0; rt < 2; ++rt)
      #pragma unroll
      for (int r = 0; r < 16; ++r) {
        int row = n0 + wid * 64 + rt * 32 + (r & 3) + 8 * (r >> 2) + 4 * h;
        out[(size_t)row * DOUTN + col] = acc[rt][r] + bval;
      }
  }
}

extern "C" void kernel_launch(void* const* d_in, const int* in_sizes, int n_in,
                              void* d_out, int out_size, void* d_ws, size_t ws_size,
                              hipStream_t stream) {
  const float* x    = (const float*)d_in[0];
  const int*   sidx = (const int*)d_in[1];
  const float* sval = (const float*)d_in[2];
  const float* Tg   = (const float*)d_in[3];
  const float* bias = (const float*)d_in[4];
  float* out = (float*)d_out;
  unsigned char* codes = (unsigned char*)d_ws;   // 1 MiB: codes[n][c]

  encode_k<<<NN / 8, 256, 0, stream>>>(x, sidx, sval, codes);
  maddness_mfma<<<dim3(16, 16), 1024, 0, stream>>>(Tg, bias, codes, out);
}

// Round 10
// 52.506 us; speedup vs baseline: 1.7775x; 1.2622x over previous
//
#include <hip/hip_runtime.h>

#define NN    16384
#define CBN   64
#define SUBV  16
#define KCODE 16
#define DOUTN 1024
#define DEP   4

typedef short bf16x8 __attribute__((ext_vector_type(8)));
typedef float f32x16 __attribute__((ext_vector_type(16)));

static __device__ __forceinline__ unsigned short f2bf(float f) {
  unsigned int u = __float_as_uint(f);
  u += 0x7FFFu + ((u >> 16) & 1u);   // RNE; inputs are normal randn, no NaN/Inf
  return (unsigned short)(u >> 16);
}

// global -> LDS direct copy, 16B/lane. LDS dest wave-uniform (HW adds lane*16).
static __device__ __forceinline__ void gld16(const void* g, void* l) {
  __builtin_amdgcn_global_load_lds(
      (const __attribute__((address_space(1))) unsigned int*)g,
      (__attribute__((address_space(3))) unsigned int*)(uintptr_t)l, 16, 0, 0);
}

// ---------------- kernel 1: table convert/swizzle + encode (fused) ----------
// blocks [0,64): build Tswz (bf16, pre-swizzled images) — first, so they
// overlap encode. blocks [64, 64+2048): encode 8 rows -> codes[n][c] u8.
// (Proven R7 kernel, unchanged.)
__global__ __launch_bounds__(256) void prep_k(
    const float* __restrict__ x, const int* __restrict__ split_idxs,
    const float* __restrict__ split_vals, const float* __restrict__ Tg,
    unsigned char* __restrict__ codes, unsigned int* __restrict__ Tswz) {
  const int t = threadIdx.x;

  if (blockIdx.x < 64) {
    const int img = blockIdx.x;                   // = g8*8 + ch
    const int g = img >> 3, ch = img & 7;
    unsigned int* dst = Tswz + (size_t)img * 8192; // 8192 u32 = 32 KiB image
    const int colq = t & 31, kp = (t >> 5) & 7;
    #pragma unroll
    for (int cl = 0; cl < 8; ++cl) {
      const float* g0 = Tg + ((size_t)((ch * 8 + cl) * KCODE + 2 * kp)) * DOUTN
                        + g * 128 + colq * 4;
      float4 r0 = *(const float4*)g0;             // k=2kp   (coalesced)
      float4 r1 = *(const float4*)(g0 + DOUTN);   // k=2kp+1
      unsigned int pk[4] = {
        f2bf(r0.x) | ((unsigned int)f2bf(r1.x) << 16),
        f2bf(r0.y) | ((unsigned int)f2bf(r1.y) << 16),
        f2bf(r0.z) | ((unsigned int)f2bf(r1.z) << 16),
        f2bf(r0.w) | ((unsigned int)f2bf(r1.w) << 16)};
      unsigned key = (unsigned)(colq & 7) << 2;   // XOR on u32-idx bits[4:2]
      #pragma unroll
      for (int j = 0; j < 4; ++j)
        dst[cl * 1024 + ((((unsigned)(colq * 4 + j)) * 8 + (unsigned)kp) ^ key)]
            = pk[j];
    }
    return;
  }

  // ---- encode ----
  __shared__ __align__(16) float xs[8][SUBV * CBN];
  __shared__ int   sidxT[DEP * CBN];               // [d][c]
  __shared__ float svalT[DEP * (KCODE / 2) * CBN]; // [d][e][c]
  if (t < DEP * CBN) {
    int d = t >> 6, c = t & 63;
    sidxT[t] = split_idxs[c * DEP + d];
  }
  for (int i = t; i < DEP * (KCODE / 2) * CBN; i += 256) {
    int c = i & 63, de = i >> 6, d = de >> 3, e = de & 7;
    svalT[i] = split_vals[(c * DEP + d) * (KCODE / 2) + e];
  }
  const int n0 = (blockIdx.x - 64) * 8;
  const float4* xg = (const float4*)(x + (size_t)n0 * DOUTN);
  #pragma unroll
  for (int i = 0; i < 8; ++i) {                    // 8 rows * 256 float4/row
    int li = t + i * 256;
    int r = li >> 8, cpos = li & 255;
    float4 v = xg[r * 256 + cpos];
    int c = cpos >> 2, q = cpos & 3;
    *(float4*)&xs[r][c * SUBV + ((q ^ (c & 3)) << 2)] = v;
  }
  __syncthreads();
  const int c = t & 63, rg = t >> 6;
  #pragma unroll
  for (int i = 0; i < 2; ++i) {
    int nl = rg * 2 + i;
    int e = 0;
    #pragma unroll
    for (int d = 0; d < DEP; ++d) {
      int si = sidxT[d * 64 + c];
      float xv = xs[nl][c * SUBV + (((si >> 2) ^ (c & 3)) << 2) + (si & 3)];
      float th = svalT[(d * 8 + e) * 64 + c];
      e = 2 * e + (xv > th ? 1 : 0);
    }
    codes[(size_t)(n0 + nl) * CBN + c] = (unsigned char)e;
  }
}

// ---------------- kernel 2: one-hot MFMA gather-accumulate ----------------
// grid (16 colgroups, 16 rowgroups) = 256 blocks = 1/CU; 1024 thr = 16 waves.
// R7 shell: stage whole 128 KiB colgroup image ONCE via gld16 (FETCH was a
// clean 6 MB, WRITE exactly 64 MiB), one barrier, free-run, SINGLE epilogue
// (R9 lesson: splitting a row's 256B write doubles HBM write traffic).
// NEW: B-fragment ds_reads batched 4-deep in two rotating half-batches
// (4-8 b128 outstanding) instead of 2 just-in-time reads per cl — removes
// the per-iteration lgkmcnt stall that capped MfmaUtil at ~25%.
__global__ __launch_bounds__(1024, 4) void maddness_mfma(
    const unsigned int* __restrict__ Tswz, const float* __restrict__ bias,
    const unsigned char* __restrict__ codes, float* __restrict__ out) {
  __shared__ __align__(16) unsigned int Tb[32768];   // 128 KiB: [ch8][cl8][512 u32]

  const int t = threadIdx.x;
  const int wid = t >> 6, lane = t & 63, lrow = lane & 31, h = lane >> 5;
  const int g16 = blockIdx.x, g8 = g16 >> 1, half = g16 & 1;
  const int n0 = blockIdx.y * 1024;
  const char* img = (const char*)Tswz + (size_t)g8 * 8 * 32768;

  // stage all 8 chunk half-images: 128 segs of 1024 B; wave stages 8 (R7 map).
  #pragma unroll
  for (int i = 0; i < 8; ++i) {
    int gs = wid * 8 + i;
    int ch = gs >> 4, s16 = gs & 15, cl = s16 >> 1, pc = s16 & 1;
    gld16(img + ch * 32768 + cl * 4096 + half * 2048 + pc * 1024 + lane * 16,
          (char*)Tb + gs * 1024);
  }

  f32x16 acc[2][2];
  #pragma unroll
  for (int rt = 0; rt < 2; ++rt)
    #pragma unroll
    for (int ct = 0; ct < 2; ++ct)
      #pragma unroll
      for (int e = 0; e < 16; ++e) acc[rt][ct][e] = 0.f;

  const unsigned char* crow0 = codes + (size_t)(n0 + wid * 64 + lrow) * CBN;
  const unsigned char* crow1 = crow0 + 32 * CBN;

  __syncthreads();                                  // the ONLY barrier

  #pragma unroll
  for (int ct = 0; ct < 2; ++ct) {
    const unsigned col_loc = (unsigned)(ct * 32 + lrow);
    const unsigned rb = (col_loc * 16 + (unsigned)h * 8)   // within-cl u16 idx
                      ^ (((col_loc >> 2) & 7u) << 3);
    const unsigned short* tb0 = (const unsigned short*)Tb + rb;

    #pragma unroll
    for (int i = 0; i < 8; ++i) {
      const int ch = (wid + i) & 7;                 // per-wave stagger
      const unsigned long long qw0 = *(const unsigned long long*)(crow0 + ch * 8);
      const unsigned long long qw1 = *(const unsigned long long*)(crow1 + ch * 8);
      const unsigned short* tbc = tb0 + ch * 8192;

      bf16x8 bva[4], bvb[4];
      #pragma unroll
      for (int k = 0; k < 4; ++k)                   // batch cl=0..3 (4 in flight)
        bva[k] = *(const bf16x8*)(tbc + k * 1024);

      #pragma unroll
      for (int hb = 0; hb < 2; ++hb) {
        if (hb == 0) {
          #pragma unroll
          for (int k = 0; k < 4; ++k)               // batch cl=4..7 while 0..3 compute
            bvb[k] = *(const bf16x8*)(tbc + (4 + k) * 1024);
        }
        #pragma unroll
        for (int k = 0; k < 4; ++k) {
          const int cl = hb * 4 + k;
          const bf16x8 bv = hb ? bvb[k] : bva[k];
          #pragma unroll
          for (int rt = 0; rt < 2; ++rt) {
            const unsigned long long q = rt ? qw1 : qw0;
            int c = (int)((q >> (8 * cl)) & 255);
            int p = c >> 1;
            unsigned s = 0x3F80u << ((c & 1) << 4); // bf16(1.0) in right half
            union { unsigned int u[4]; bf16x8 v; } A;
            #pragma unroll
            for (int j = 0; j < 4; ++j) A.u[j] = (p == h * 4 + j) ? s : 0u;
            acc[rt][ct] = __builtin_amdgcn_mfma_f32_32x32x16_bf16(A.v, bv, acc[rt][ct], 0, 0, 0);
          }
        }
      }
    }
  }

  // single epilogue: D layout col=lane&31, row=(reg&3)+8*(reg>>2)+4*(lane>>5)
  #pragma unroll
  for (int ct = 0; ct < 2; ++ct) {
    const int col = g16 * 64 + ct * 32 + lrow;
    const float bval = bias[col];
    #pragma unroll
    for (int rt = 0; rt < 2; ++rt)
      #pragma unroll
      for (int r = 0; r < 16; ++r) {
        int row = n0 + wid * 64 + rt * 32 + (r & 3) + 8 * (r >> 2) + 4 * h;
        out[(size_t)row * DOUTN + col] = acc[rt][ct][r] + bval;
      }
  }
}

extern "C" void kernel_launch(void* const* d_in, const int* in_sizes, int n_in,
                              void* d_out, int out_size, void* d_ws, size_t ws_size,
                              hipStream_t stream) {
  const float* x    = (const float*)d_in[0];
  const int*   sidx = (const int*)d_in[1];
  const float* sval = (const float*)d_in[2];
  const float* Tg   = (const float*)d_in[3];
  const float* bias = (const float*)d_in[4];
  float* out = (float*)d_out;
  unsigned char* codes = (unsigned char*)d_ws;                       // 1 MiB
  unsigned int*  Tswz  = (unsigned int*)((char*)d_ws + (1 << 20));   // 2 MiB

  prep_k<<<64 + NN / 8, 256, 0, stream>>>(x, sidx, sval, Tg, codes, Tswz);
  maddness_mfma<<<dim3(16, 16), 1024, 0, stream>>>(Tswz, bias, codes, out);
}